// Round 1
// 537.580 us; speedup vs baseline: 1.2652x; 1.2652x over previous
//
#include <hip/hip_runtime.h>
#include <math.h>

#define BB 4
#define SS 1024
#define HH 12
#define DD 32
#define HIDDEN 768
#define AHS 384
#define RQ 8
#define HEAD_ELEMS (SS*DD)      // 32768
#define CTX_ELEMS (BB*SS*AHS)   // 1572864

__device__ __forceinline__ float clampf(float x, float lo, float hi){ return fminf(fmaxf(x, lo), hi); }

// ---------------------------------------------------------------------------
// Kernel 1: fused QKV projection. C = X @ W^T + b, 4 weight mats as one
// [4096 x 1536] GEMM. 128x64 tile, 8x4 micro-tile, global->reg prefetch.
// q,v stored [BH,S,D]; k1,k2 TRANSPOSED [BH,D,S].
// ---------------------------------------------------------------------------
__global__ __launch_bounds__(256)
void proj_kernel(const float* __restrict__ X,
                 const float* __restrict__ W0, const float* __restrict__ b0,
                 const float* __restrict__ W1, const float* __restrict__ b1,
                 const float* __restrict__ W2, const float* __restrict__ b2,
                 const float* __restrict__ W3, const float* __restrict__ b3,
                 float* __restrict__ qo, float* __restrict__ k1o,
                 float* __restrict__ k2o, float* __restrict__ vo)
{
    const int BM = 128, BN = 64, BK = 16;
    __shared__ float Xs[BK][BM + 4];
    __shared__ float Wsh[BK][BN + 4];
    int t  = threadIdx.x;
    int m0 = blockIdx.x * BM;
    int n0 = blockIdx.y * BN;
    int mat = n0 / AHS;
    int c0  = n0 % AHS;
    const float* W    = (mat==0) ? W0 : (mat==1) ? W1 : (mat==2) ? W2 : W3;
    const float* bias = (mat==0) ? b0 : (mat==1) ? b1 : (mat==2) ? b2 : b3;

    int tx = t & 15, ty = t >> 4;       // micro-tile: rows ty*8..+8, cols tx*4..+4
    int lr = t >> 2;                    // 0..63
    int lc = (t & 3) << 2;              // 0,4,8,12

    float acc[8][4];
    #pragma unroll
    for (int i = 0; i < 8; i++)
        #pragma unroll
        for (int j = 0; j < 4; j++) acc[i][j] = 0.f;

    float4 xa = *(const float4*)(X + (m0 + lr) * HIDDEN + lc);
    float4 xb = *(const float4*)(X + (m0 + 64 + lr) * HIDDEN + lc);
    float4 wa = *(const float4*)(W + (c0 + lr) * HIDDEN + lc);

    for (int k0 = 0; k0 < HIDDEN; k0 += BK) {
        __syncthreads();
        Xs[lc+0][lr] = xa.x; Xs[lc+1][lr] = xa.y; Xs[lc+2][lr] = xa.z; Xs[lc+3][lr] = xa.w;
        Xs[lc+0][64+lr] = xb.x; Xs[lc+1][64+lr] = xb.y; Xs[lc+2][64+lr] = xb.z; Xs[lc+3][64+lr] = xb.w;
        Wsh[lc+0][lr] = wa.x; Wsh[lc+1][lr] = wa.y; Wsh[lc+2][lr] = wa.z; Wsh[lc+3][lr] = wa.w;
        __syncthreads();
        if (k0 + BK < HIDDEN) {   // prefetch next tile during compute
            xa = *(const float4*)(X + (m0 + lr) * HIDDEN + k0 + BK + lc);
            xb = *(const float4*)(X + (m0 + 64 + lr) * HIDDEN + k0 + BK + lc);
            wa = *(const float4*)(W + (c0 + lr) * HIDDEN + k0 + BK + lc);
        }
        #pragma unroll
        for (int kk = 0; kk < BK; kk++) {
            float a[8], w4[4];
            *(float4*)&a[0] = *(const float4*)&Xs[kk][ty << 3];
            *(float4*)&a[4] = *(const float4*)&Xs[kk][(ty << 3) + 4];
            *(float4*)w4    = *(const float4*)&Wsh[kk][tx << 2];
            #pragma unroll
            for (int i = 0; i < 8; i++)
                #pragma unroll
                for (int j = 0; j < 4; j++)
                    acc[i][j] = fmaf(a[i], w4[j], acc[i][j]);
        }
    }

    #pragma unroll
    for (int i = 0; i < 8; i++) {
        int row = m0 + (ty << 3) + i;
        int b_  = row >> 10;
        int s   = row & 1023;
        #pragma unroll
        for (int j = 0; j < 4; j++) {
            int c = c0 + (tx << 2) + j;
            int h = c >> 5, d = c & 31;
            int bh = b_ * HH + h;
            float val = acc[i][j] + bias[c];
            if (mat == 0)      qo [(bh * SS + s) * DD + d] = val;
            else if (mat == 1) k1o[(bh * DD + d) * SS + s] = val;
            else if (mat == 2) k2o[(bh * DD + d) * SS + s] = val;
            else               vo [(bh * SS + s) * DD + d] = val;
        }
    }
}

// ---------------------------------------------------------------------------
// Kernel 2: per-row squared norms of k1,k2 from the transposed layout.
// ---------------------------------------------------------------------------
__global__ __launch_bounds__(256)
void norms_kernel(const float* __restrict__ k1T, const float* __restrict__ k2T,
                  float* __restrict__ n1, float* __restrict__ n2)
{
    int bh = blockIdx.y;
    int s  = blockIdx.x * 256 + threadIdx.x;
    const float* p1 = k1T + bh * HEAD_ELEMS + s;
    const float* p2 = k2T + bh * HEAD_ELEMS + s;
    float a1 = 0.f, a2 = 0.f;
    #pragma unroll
    for (int d = 0; d < DD; d++) {
        float x1 = p1[d * SS]; a1 = fmaf(x1, x1, a1);
        float x2 = p2[d * SS]; a2 = fmaf(x2, x2, a2);
    }
    n1[bh * SS + s] = a1;
    n2[bh * SS + s] = a2;
}

// ---------------------------------------------------------------------------
// Kernel 3: FUSED scores + softmax-mixture + probs write + ctx = P @ V.
// One WG per (bh, 8 rows). Phases 1-3 as before (scores in VGPRs). Phase 3
// additionally stashes the normalized 8x1024 P tile in LDS (32 KB, XOR-
// swizzled [k][r] layout so phase-4 b128 reads are 2-way/free). Phase 4:
// thread = (k-slice ks 0..31, d-quad c4 0..7); 32 iters of
// {2x ds_read_b128 (P row, broadcast) + float4 v load (coalesced, each v
// byte read exactly once per WG) + 32 FMA}; then LDS cross-slice reduce.
// This removes the separate pv_kernel and its 200 MB probs re-read, which
// was latency-bound at 8% HBM / 13% VALU.
// LDS: 32 KB p_s + 1 KB q + scratch = 33.3 KB -> 4 WG/CU, matching the
// VGPR-bound 4 waves/SIMD from launch_bounds.
// ---------------------------------------------------------------------------
__global__ __launch_bounds__(256, 4)
void attn_fused(const float* __restrict__ qg,  const float* __restrict__ k1T,
                const float* __restrict__ k2T,
                const float* __restrict__ n1g, const float* __restrict__ n2g,
                const float* __restrict__ maskg, const float* __restrict__ pig,
                const float* __restrict__ vg,
                float* __restrict__ probs, float* __restrict__ ctx)
{
    const float A1C = 0.08838834764831845f;   // SCALING/2
    const float A2C = 0.13258252147247767f;   // 1.5*SCALING/2
    __shared__ float p_s[RQ * SS];            // 32 KB: P tile, then PV partials
    __shared__ float q_s[RQ * DD];
    __shared__ float red1[4][RQ], red2[4][RQ];
    __shared__ float qn_s[RQ];

    int t    = threadIdx.x;
    int lane = t & 63, wid = t >> 6;
    int bh   = blockIdx.y;
    int b    = bh / HH, h = bh - b * HH;
    int s0   = blockIdx.x * RQ;

    q_s[t] = qg[(bh * SS + s0) * DD + t];
    __syncthreads();
    if (t < RQ) {
        float a = 0.f;
        for (int d = 0; d < DD; d++) { float x = q_s[t * DD + d]; a = fmaf(x, x, a); }
        qn_s[t] = a;
    }
    __syncthreads();

    float pi0 = clampf(pig[h],      1e-6f, 2.0f);
    float pi1 = clampf(pig[HH + h], 1e-6f, 2.0f);

    float e1r[4][RQ], e2r[4][RQ];
    float pm1[RQ], pm2[RQ];
    #pragma unroll
    for (int r = 0; r < RQ; r++) { pm1[r] = -3.4e38f; pm2[r] = -3.4e38f; }

    const float* k1p = k1T + bh * HEAD_ELEMS;
    const float* k2p = k2T + bh * HEAD_ELEMS;
    const float* n1p = n1g + bh * SS;
    const float* n2p = n2g + bh * SS;
    const float* mp  = maskg + b * SS;

    // ---- phase 1: dots + scores -------------------------------------------
    #pragma unroll
    for (int j = 0; j < 4; j++) {
        int k = j * 256 + t;
        float n1k = n1p[k], n2k = n2p[k], mk = mp[k];
        float c1[RQ], c2[RQ];
        #pragma unroll
        for (int r = 0; r < RQ; r++) { c1[r] = 0.f; c2[r] = 0.f; }
        #pragma unroll
        for (int d4 = 0; d4 < 8; d4++) {
            float kv1[4], kv2[4];
            #pragma unroll
            for (int dd = 0; dd < 4; dd++) {
                kv1[dd] = k1p[(d4 * 4 + dd) * SS + k];
                kv2[dd] = k2p[(d4 * 4 + dd) * SS + k];
            }
            #pragma unroll
            for (int r = 0; r < RQ; r++) {
                float qv[4];
                *(float4*)qv = *(const float4*)&q_s[r * DD + d4 * 4];
                #pragma unroll
                for (int dd = 0; dd < 4; dd++) {
                    c1[r] = fmaf(qv[dd], kv1[dd], c1[r]);
                    c2[r] = fmaf(qv[dd], kv2[dd], c2[r]);
                }
            }
        }
        #pragma unroll
        for (int r = 0; r < RQ; r++) {
            float qn  = qn_s[r];
            float d1v = fmaxf(fmaf(-2.f, c1[r], qn + n1k), 0.f);
            float d2v = fmaxf(fmaf(-2.f, c2[r], qn + n2k), 0.f);
            float ev1 = fmaf(-A1C, d1v, mk);
            float ev2 = fmaf(-A2C, d2v, mk);
            e1r[j][r] = ev1;
            e2r[j][r] = ev2;
            pm1[r] = fmaxf(pm1[r], ev1);
            pm2[r] = fmaxf(pm2[r], ev2);
        }
    }

    // ---- row max (both sets, one barrier pair) ----------------------------
    #pragma unroll
    for (int off = 32; off >= 1; off >>= 1)
        #pragma unroll
        for (int r = 0; r < RQ; r++) {
            pm1[r] = fmaxf(pm1[r], __shfl_xor(pm1[r], off));
            pm2[r] = fmaxf(pm2[r], __shfl_xor(pm2[r], off));
        }
    if (lane == 0) {
        #pragma unroll
        for (int r = 0; r < RQ; r++) { red1[wid][r] = pm1[r]; red2[wid][r] = pm2[r]; }
    }
    __syncthreads();
    float m1[RQ], m2[RQ];
    #pragma unroll
    for (int r = 0; r < RQ; r++) {
        m1[r] = fmaxf(fmaxf(red1[0][r], red1[1][r]), fmaxf(red1[2][r], red1[3][r]));
        m2[r] = fmaxf(fmaxf(red2[0][r], red2[1][r]), fmaxf(red2[2][r], red2[3][r]));
    }

    // ---- phase 2: exp + mixture, row sums ---------------------------------
    float ps[RQ];
    #pragma unroll
    for (int r = 0; r < RQ; r++) ps[r] = 0.f;
    #pragma unroll
    for (int j = 0; j < 4; j++)
        #pragma unroll
        for (int r = 0; r < RQ; r++) {
            float p = pi0 * __expf(e1r[j][r] - m1[r]) + pi1 * __expf(e2r[j][r] - m2[r]);
            e1r[j][r] = p;
            ps[r] += p;
        }

    #pragma unroll
    for (int off = 32; off >= 1; off >>= 1)
        #pragma unroll
        for (int r = 0; r < RQ; r++) ps[r] += __shfl_xor(ps[r], off);
    __syncthreads();
    if (lane == 0) {
        #pragma unroll
        for (int r = 0; r < RQ; r++) red1[wid][r] = ps[r];
    }
    __syncthreads();
    float inv[RQ];
    #pragma unroll
    for (int r = 0; r < RQ; r++) {
        float sum = red1[0][r] + red1[1][r] + red1[2][r] + red1[3][r];
        inv[r] = 1.0f / (sum + 1e-6f);
    }

    // ---- phase 3: normalize + write probs (global) + stash P in LDS -------
    // LDS layout: element (k, r) at float index ((k<<3)+r) ^ (((k>>5)&3)<<3).
    // The XOR of bits 3..4 with (k-slice & 3) makes phase-4's 8 distinct
    // per-wave b128 addresses land in 4 bank groups (2-way = free).
    float* prow = probs + (size_t)(bh * SS + s0) * SS;
    #pragma unroll
    for (int j = 0; j < 4; j++) {
        int k = (j << 8) + t;
        float pv8[8];
        #pragma unroll
        for (int r = 0; r < RQ; r++) pv8[r] = e1r[j][r] * inv[r];
        #pragma unroll
        for (int r = 0; r < RQ; r++) prow[(size_t)r * SS + k] = pv8[r];
        int base = (k << 3) ^ (((k >> 5) & 3) << 3);
        *(float4*)&p_s[base]     = *(float4*)&pv8[0];
        *(float4*)&p_s[base + 4] = *(float4*)&pv8[4];
    }
    __syncthreads();

    // ---- phase 4a: partial PV. thread = (ks 0..31, c4 0..7) ---------------
    {
        int ks = t >> 3;                 // k slice: 32 consecutive k
        int c4 = t & 7;                  // d-quad: columns c4*4 .. +4
        int swzc = (ks & 3) << 3;
        const float* vp = vg + bh * HEAD_ELEMS + (c4 << 2);
        float4 acc4[RQ];
        #pragma unroll
        for (int r = 0; r < RQ; r++) acc4[r] = make_float4(0.f, 0.f, 0.f, 0.f);
        #pragma unroll 4
        for (int kk = 0; kk < 32; kk++) {
            int k = (ks << 5) + kk;
            int base = (k << 3) ^ swzc;
            float pr[8];
            *(float4*)&pr[0] = *(const float4*)&p_s[base];
            *(float4*)&pr[4] = *(const float4*)&p_s[base + 4];
            float4 vv = *(const float4*)&vp[k << 5];
            #pragma unroll
            for (int r = 0; r < RQ; r++) {
                acc4[r].x = fmaf(pr[r], vv.x, acc4[r].x);
                acc4[r].y = fmaf(pr[r], vv.y, acc4[r].y);
                acc4[r].z = fmaf(pr[r], vv.z, acc4[r].z);
                acc4[r].w = fmaf(pr[r], vv.w, acc4[r].w);
            }
        }
        __syncthreads();                 // all P reads done; reuse p_s
        // partials: element (ks, r, d) at ((ks<<8)+(r<<5)+d) ^ ((ks&3)<<3)
        #pragma unroll
        for (int r = 0; r < RQ; r++)
            *(float4*)&p_s[((ks << 8) + (r << 5) + (c4 << 2)) ^ ((ks & 3) << 3)] = acc4[r];
    }
    __syncthreads();

    // ---- phase 4b: cross-slice reduce + ctx store -------------------------
    {
        int rr = t >> 5, dd = t & 31;
        float o = 0.f;
        #pragma unroll
        for (int s2 = 0; s2 < 32; s2++)
            o += p_s[((s2 << 8) + (rr << 5) + dd) ^ ((s2 & 3) << 3)];
        ctx[((size_t)(b * SS + s0 + rr) * HH + h) * DD + dd] = o;
    }
}

// ---------------------------------------------------------------------------
extern "C" void kernel_launch(void* const* d_in, const int* in_sizes, int n_in,
                              void* d_out, int out_size, void* d_ws, size_t ws_size,
                              hipStream_t stream)
{
    const float* hs   = (const float*)d_in[0];
    const float* mask = (const float*)d_in[1];
    const float* Wq   = (const float*)d_in[2];
    const float* bq   = (const float*)d_in[3];
    const float* Wk1  = (const float*)d_in[4];
    const float* bk1  = (const float*)d_in[5];
    const float* Wk2  = (const float*)d_in[6];
    const float* bk2  = (const float*)d_in[7];
    const float* Wv   = (const float*)d_in[8];
    const float* bv   = (const float*)d_in[9];
    const float* pi   = (const float*)d_in[10];

    float* ws   = (float*)d_ws;
    float* q_ws = ws;
    float* v_ws = ws + (size_t)CTX_ELEMS * 1;
    float* k1T  = ws + (size_t)CTX_ELEMS * 2;
    float* k2T  = ws + (size_t)CTX_ELEMS * 3;
    float* n1   = ws + (size_t)CTX_ELEMS * 4;
    float* n2   = n1 + BB * HH * SS;

    float* ctx   = (float*)d_out;
    float* probs = ctx + CTX_ELEMS;

    proj_kernel<<<dim3(32, 24), 256, 0, stream>>>(hs, Wq, bq, Wk1, bk1, Wk2, bk2,
                                                  Wv, bv, q_ws, k1T, k2T, v_ws);
    norms_kernel<<<dim3(SS / 256, BB * HH), 256, 0, stream>>>(k1T, k2T, n1, n2);
    attn_fused<<<dim3(SS / RQ, BB * HH), 256, 0, stream>>>(q_ws, k1T, k2T,
                                                           n1, n2, mask, pi,
                                                           v_ws, probs, ctx);
}

// Round 2
// 519.903 us; speedup vs baseline: 1.3082x; 1.0340x over previous
//
#include <hip/hip_runtime.h>
#include <math.h>

#define BB 4
#define SS 1024
#define HH 12
#define DD 32
#define HIDDEN 768
#define AHS 384
#define RQ 8
#define HEAD_ELEMS (SS*DD)      // 32768
#define CTX_ELEMS (BB*SS*AHS)   // 1572864

__device__ __forceinline__ float clampf(float x, float lo, float hi){ return fminf(fmaxf(x, lo), hi); }

// ---------------------------------------------------------------------------
// Kernel 1: fused QKV projection. C = X @ W^T + b, 4 weight mats as one
// [4096 x 1536] GEMM. 128x64 tile, 8x4 micro-tile, global->reg prefetch.
// q,v stored [BH,S,D]; k1,k2 stored INTERLEAVED [BH, D/4, S, 4] so the
// attention kernel can fetch 4 d-values per key with one float4 load.
// All epilogue stores are float4 (the 4 j-columns of a thread are one
// d-quad of one head).
// ---------------------------------------------------------------------------
__global__ __launch_bounds__(256)
void proj_kernel(const float* __restrict__ X,
                 const float* __restrict__ W0, const float* __restrict__ b0,
                 const float* __restrict__ W1, const float* __restrict__ b1,
                 const float* __restrict__ W2, const float* __restrict__ b2,
                 const float* __restrict__ W3, const float* __restrict__ b3,
                 float* __restrict__ qo, float* __restrict__ k1o,
                 float* __restrict__ k2o, float* __restrict__ vo)
{
    const int BM = 128, BN = 64, BK = 16;
    __shared__ float Xs[BK][BM + 4];
    __shared__ float Wsh[BK][BN + 4];
    int t  = threadIdx.x;
    int m0 = blockIdx.x * BM;
    int n0 = blockIdx.y * BN;
    int mat = n0 / AHS;
    int c0  = n0 % AHS;
    const float* W    = (mat==0) ? W0 : (mat==1) ? W1 : (mat==2) ? W2 : W3;
    const float* bias = (mat==0) ? b0 : (mat==1) ? b1 : (mat==2) ? b2 : b3;

    int tx = t & 15, ty = t >> 4;       // micro-tile: rows ty*8..+8, cols tx*4..+4
    int lr = t >> 2;                    // 0..63
    int lc = (t & 3) << 2;              // 0,4,8,12

    float acc[8][4];
    #pragma unroll
    for (int i = 0; i < 8; i++)
        #pragma unroll
        for (int j = 0; j < 4; j++) acc[i][j] = 0.f;

    float4 xa = *(const float4*)(X + (m0 + lr) * HIDDEN + lc);
    float4 xb = *(const float4*)(X + (m0 + 64 + lr) * HIDDEN + lc);
    float4 wa = *(const float4*)(W + (c0 + lr) * HIDDEN + lc);

    for (int k0 = 0; k0 < HIDDEN; k0 += BK) {
        __syncthreads();
        Xs[lc+0][lr] = xa.x; Xs[lc+1][lr] = xa.y; Xs[lc+2][lr] = xa.z; Xs[lc+3][lr] = xa.w;
        Xs[lc+0][64+lr] = xb.x; Xs[lc+1][64+lr] = xb.y; Xs[lc+2][64+lr] = xb.z; Xs[lc+3][64+lr] = xb.w;
        Wsh[lc+0][lr] = wa.x; Wsh[lc+1][lr] = wa.y; Wsh[lc+2][lr] = wa.z; Wsh[lc+3][lr] = wa.w;
        __syncthreads();
        if (k0 + BK < HIDDEN) {   // prefetch next tile during compute
            xa = *(const float4*)(X + (m0 + lr) * HIDDEN + k0 + BK + lc);
            xb = *(const float4*)(X + (m0 + 64 + lr) * HIDDEN + k0 + BK + lc);
            wa = *(const float4*)(W + (c0 + lr) * HIDDEN + k0 + BK + lc);
        }
        #pragma unroll
        for (int kk = 0; kk < BK; kk++) {
            float a[8], w4[4];
            *(float4*)&a[0] = *(const float4*)&Xs[kk][ty << 3];
            *(float4*)&a[4] = *(const float4*)&Xs[kk][(ty << 3) + 4];
            *(float4*)w4    = *(const float4*)&Wsh[kk][tx << 2];
            #pragma unroll
            for (int i = 0; i < 8; i++)
                #pragma unroll
                for (int j = 0; j < 4; j++)
                    acc[i][j] = fmaf(a[i], w4[j], acc[i][j]);
        }
    }

    int cbase = c0 + (tx << 2);          // multiple of 4; one d-quad, one head
    int h  = (cbase >> 5) % HH;
    int d0 = cbase & 31;
    int d4 = d0 >> 2;
    float4 bq4 = *(const float4*)(bias + cbase);

    #pragma unroll
    for (int i = 0; i < 8; i++) {
        int row = m0 + (ty << 3) + i;
        int b_  = row >> 10;
        int s   = row & 1023;
        int bh  = b_ * HH + h;
        float4 val;
        val.x = acc[i][0] + bq4.x;
        val.y = acc[i][1] + bq4.y;
        val.z = acc[i][2] + bq4.z;
        val.w = acc[i][3] + bq4.w;
        if (mat == 0)
            *(float4*)&qo[((size_t)(bh * SS + s)) * DD + d0] = val;
        else if (mat == 1)
            *(float4*)&k1o[((size_t)(bh * 8 + d4) * SS + s) * 4] = val;
        else if (mat == 2)
            *(float4*)&k2o[((size_t)(bh * 8 + d4) * SS + s) * 4] = val;
        else
            *(float4*)&vo[((size_t)(bh * SS + s)) * DD + d0] = val;
    }
}

// ---------------------------------------------------------------------------
// Kernel 2: per-row squared norms of k1,k2 from the interleaved layout.
// float4 loads, coalesced across s.
// ---------------------------------------------------------------------------
__global__ __launch_bounds__(256)
void norms_kernel(const float* __restrict__ k1i, const float* __restrict__ k2i,
                  float* __restrict__ n1, float* __restrict__ n2)
{
    int bh = blockIdx.y;
    int s  = blockIdx.x * 256 + threadIdx.x;
    const float* p1 = k1i + (size_t)bh * (8 * SS * 4) + s * 4;
    const float* p2 = k2i + (size_t)bh * (8 * SS * 4) + s * 4;
    float a1 = 0.f, a2 = 0.f;
    #pragma unroll
    for (int d4 = 0; d4 < 8; d4++) {
        float4 v1 = *(const float4*)&p1[(size_t)d4 * SS * 4];
        float4 v2 = *(const float4*)&p2[(size_t)d4 * SS * 4];
        a1 = fmaf(v1.x, v1.x, a1); a1 = fmaf(v1.y, v1.y, a1);
        a1 = fmaf(v1.z, v1.z, a1); a1 = fmaf(v1.w, v1.w, a1);
        a2 = fmaf(v2.x, v2.x, a2); a2 = fmaf(v2.y, v2.y, a2);
        a2 = fmaf(v2.z, v2.z, a2); a2 = fmaf(v2.w, v2.w, a2);
    }
    n1[bh * SS + s] = a1;
    n2[bh * SS + s] = a2;
}

// ---------------------------------------------------------------------------
// Kernel 3: FUSED scores + softmax-mixture + probs write + ctx = P @ V.
// One WG per (bh, 8 rows); 1-D grid with XCD-aware swizzle so each XCD's L2
// holds the k/v of ~6 consecutive heads.
// Changes vs prev round:
//  - k1/k2 read as float4 from the interleaved [bh][d4][s][4] layout:
//    phase-1 global loads drop 512 scalar -> 64 b128 per wave (kills ~2k cyc
//    of 64-bit address VALU and pipelines much deeper).
//  - probs + ctx written with nontemporal stores: the 201 MB probs stream no
//    longer evicts k/v/q from L3 (FETCH_SIZE was 138 MB vs 38 MB of input).
// ---------------------------------------------------------------------------
__global__ __launch_bounds__(256, 4)
void attn_fused(const float* __restrict__ qg,  const float* __restrict__ k1i,
                const float* __restrict__ k2i,
                const float* __restrict__ n1g, const float* __restrict__ n2g,
                const float* __restrict__ maskg, const float* __restrict__ pig,
                const float* __restrict__ vg,
                float* __restrict__ probs, float* __restrict__ ctx)
{
    const float A1C = 0.08838834764831845f;   // SCALING/2
    const float A2C = 0.13258252147247767f;   // 1.5*SCALING/2
    __shared__ float p_s[RQ * SS];            // 32 KB: P tile, then PV partials
    __shared__ float q_s[RQ * DD];
    __shared__ float red1[4][RQ], red2[4][RQ];
    __shared__ float qn_s[RQ];

    int t    = threadIdx.x;
    int lane = t & 63, wid = t >> 6;

    // XCD swizzle: 6144 blocks, 8 XCDs -> each XCD gets 768 consecutive
    // swizzled ids = 6 consecutive bh values (k1+k2+v = 2.3 MB, fits 4 MB L2).
    int bid = blockIdx.x;
    int swz = (bid & 7) * 768 + (bid >> 3);
    int bh  = swz >> 7;
    int s0  = (swz & 127) * RQ;
    int b   = bh / HH, h = bh - b * HH;

    q_s[t] = qg[(bh * SS + s0) * DD + t];
    __syncthreads();
    if (t < RQ) {
        float a = 0.f;
        for (int d = 0; d < DD; d++) { float x = q_s[t * DD + d]; a = fmaf(x, x, a); }
        qn_s[t] = a;
    }
    __syncthreads();

    float pi0 = clampf(pig[h],      1e-6f, 2.0f);
    float pi1 = clampf(pig[HH + h], 1e-6f, 2.0f);

    float e1r[4][RQ], e2r[4][RQ];
    float pm1[RQ], pm2[RQ];
    #pragma unroll
    for (int r = 0; r < RQ; r++) { pm1[r] = -3.4e38f; pm2[r] = -3.4e38f; }

    const float* k1p = k1i + (size_t)bh * (8 * SS * 4);   // [d4][s][4]
    const float* k2p = k2i + (size_t)bh * (8 * SS * 4);
    const float* n1p = n1g + bh * SS;
    const float* n2p = n2g + bh * SS;
    const float* mp  = maskg + b * SS;

    // ---- phase 1: dots + scores -------------------------------------------
    #pragma unroll
    for (int j = 0; j < 4; j++) {
        int k = j * 256 + t;
        float n1k = n1p[k], n2k = n2p[k], mk = mp[k];
        float c1[RQ], c2[RQ];
        #pragma unroll
        for (int r = 0; r < RQ; r++) { c1[r] = 0.f; c2[r] = 0.f; }
        #pragma unroll
        for (int d4 = 0; d4 < 8; d4++) {
            float4 kq1 = *(const float4*)&k1p[((size_t)d4 * SS + k) * 4];
            float4 kq2 = *(const float4*)&k2p[((size_t)d4 * SS + k) * 4];
            const float* kv1 = (const float*)&kq1;
            const float* kv2 = (const float*)&kq2;
            #pragma unroll
            for (int r = 0; r < RQ; r++) {
                float qv[4];
                *(float4*)qv = *(const float4*)&q_s[r * DD + d4 * 4];
                #pragma unroll
                for (int dd = 0; dd < 4; dd++) {
                    c1[r] = fmaf(qv[dd], kv1[dd], c1[r]);
                    c2[r] = fmaf(qv[dd], kv2[dd], c2[r]);
                }
            }
        }
        #pragma unroll
        for (int r = 0; r < RQ; r++) {
            float qn  = qn_s[r];
            float d1v = fmaxf(fmaf(-2.f, c1[r], qn + n1k), 0.f);
            float d2v = fmaxf(fmaf(-2.f, c2[r], qn + n2k), 0.f);
            float ev1 = fmaf(-A1C, d1v, mk);
            float ev2 = fmaf(-A2C, d2v, mk);
            e1r[j][r] = ev1;
            e2r[j][r] = ev2;
            pm1[r] = fmaxf(pm1[r], ev1);
            pm2[r] = fmaxf(pm2[r], ev2);
        }
    }

    // ---- row max (both sets, one barrier pair) ----------------------------
    #pragma unroll
    for (int off = 32; off >= 1; off >>= 1)
        #pragma unroll
        for (int r = 0; r < RQ; r++) {
            pm1[r] = fmaxf(pm1[r], __shfl_xor(pm1[r], off));
            pm2[r] = fmaxf(pm2[r], __shfl_xor(pm2[r], off));
        }
    if (lane == 0) {
        #pragma unroll
        for (int r = 0; r < RQ; r++) { red1[wid][r] = pm1[r]; red2[wid][r] = pm2[r]; }
    }
    __syncthreads();
    float m1[RQ], m2[RQ];
    #pragma unroll
    for (int r = 0; r < RQ; r++) {
        m1[r] = fmaxf(fmaxf(red1[0][r], red1[1][r]), fmaxf(red1[2][r], red1[3][r]));
        m2[r] = fmaxf(fmaxf(red2[0][r], red2[1][r]), fmaxf(red2[2][r], red2[3][r]));
    }

    // ---- phase 2: exp + mixture, row sums ---------------------------------
    float ps[RQ];
    #pragma unroll
    for (int r = 0; r < RQ; r++) ps[r] = 0.f;
    #pragma unroll
    for (int j = 0; j < 4; j++)
        #pragma unroll
        for (int r = 0; r < RQ; r++) {
            float p = pi0 * __expf(e1r[j][r] - m1[r]) + pi1 * __expf(e2r[j][r] - m2[r]);
            e1r[j][r] = p;
            ps[r] += p;
        }

    #pragma unroll
    for (int off = 32; off >= 1; off >>= 1)
        #pragma unroll
        for (int r = 0; r < RQ; r++) ps[r] += __shfl_xor(ps[r], off);
    __syncthreads();
    if (lane == 0) {
        #pragma unroll
        for (int r = 0; r < RQ; r++) red1[wid][r] = ps[r];
    }
    __syncthreads();
    float inv[RQ];
    #pragma unroll
    for (int r = 0; r < RQ; r++) {
        float sum = red1[0][r] + red1[1][r] + red1[2][r] + red1[3][r];
        inv[r] = 1.0f / (sum + 1e-6f);
    }

    // ---- phase 3: normalize + NT-write probs + stash P in LDS -------------
    // LDS layout: element (k, r) at float index ((k<<3)+r) ^ (((k>>5)&3)<<3).
    float* prow = probs + (size_t)(bh * SS + s0) * SS;
    #pragma unroll
    for (int j = 0; j < 4; j++) {
        int k = (j << 8) + t;
        float pv8[8];
        #pragma unroll
        for (int r = 0; r < RQ; r++) pv8[r] = e1r[j][r] * inv[r];
        #pragma unroll
        for (int r = 0; r < RQ; r++)
            __builtin_nontemporal_store(pv8[r], &prow[(size_t)r * SS + k]);
        int base = (k << 3) ^ (((k >> 5) & 3) << 3);
        *(float4*)&p_s[base]     = *(float4*)&pv8[0];
        *(float4*)&p_s[base + 4] = *(float4*)&pv8[4];
    }
    __syncthreads();

    // ---- phase 4a: partial PV. thread = (ks 0..31, c4 0..7) ---------------
    {
        int ks = t >> 3;                 // k slice: 32 consecutive k
        int c4 = t & 7;                  // d-quad: columns c4*4 .. +4
        int swzc = (ks & 3) << 3;
        const float* vp = vg + bh * HEAD_ELEMS + (c4 << 2);
        float4 acc4[RQ];
        #pragma unroll
        for (int r = 0; r < RQ; r++) acc4[r] = make_float4(0.f, 0.f, 0.f, 0.f);
        #pragma unroll 4
        for (int kk = 0; kk < 32; kk++) {
            int k = (ks << 5) + kk;
            int base = (k << 3) ^ swzc;
            float pr[8];
            *(float4*)&pr[0] = *(const float4*)&p_s[base];
            *(float4*)&pr[4] = *(const float4*)&p_s[base + 4];
            float4 vv = *(const float4*)&vp[k << 5];
            #pragma unroll
            for (int r = 0; r < RQ; r++) {
                acc4[r].x = fmaf(pr[r], vv.x, acc4[r].x);
                acc4[r].y = fmaf(pr[r], vv.y, acc4[r].y);
                acc4[r].z = fmaf(pr[r], vv.z, acc4[r].z);
                acc4[r].w = fmaf(pr[r], vv.w, acc4[r].w);
            }
        }
        __syncthreads();                 // all P reads done; reuse p_s
        // partials: element (ks, r, d) at ((ks<<8)+(r<<5)+d) ^ ((ks&3)<<3)
        #pragma unroll
        for (int r = 0; r < RQ; r++)
            *(float4*)&p_s[((ks << 8) + (r << 5) + (c4 << 2)) ^ ((ks & 3) << 3)] = acc4[r];
    }
    __syncthreads();

    // ---- phase 4b: cross-slice reduce + NT ctx store ----------------------
    {
        int rr = t >> 5, dd = t & 31;
        float o = 0.f;
        #pragma unroll
        for (int s2 = 0; s2 < 32; s2++)
            o += p_s[((s2 << 8) + (rr << 5) + dd) ^ ((s2 & 3) << 3)];
        __builtin_nontemporal_store(o, &ctx[((size_t)(b * SS + s0 + rr) * HH + h) * DD + dd]);
    }
}

// ---------------------------------------------------------------------------
extern "C" void kernel_launch(void* const* d_in, const int* in_sizes, int n_in,
                              void* d_out, int out_size, void* d_ws, size_t ws_size,
                              hipStream_t stream)
{
    const float* hs   = (const float*)d_in[0];
    const float* mask = (const float*)d_in[1];
    const float* Wq   = (const float*)d_in[2];
    const float* bq   = (const float*)d_in[3];
    const float* Wk1  = (const float*)d_in[4];
    const float* bk1  = (const float*)d_in[5];
    const float* Wk2  = (const float*)d_in[6];
    const float* bk2  = (const float*)d_in[7];
    const float* Wv   = (const float*)d_in[8];
    const float* bv   = (const float*)d_in[9];
    const float* pi   = (const float*)d_in[10];

    float* ws   = (float*)d_ws;
    float* q_ws = ws;
    float* v_ws = ws + (size_t)CTX_ELEMS * 1;
    float* k1T  = ws + (size_t)CTX_ELEMS * 2;
    float* k2T  = ws + (size_t)CTX_ELEMS * 3;
    float* n1   = ws + (size_t)CTX_ELEMS * 4;
    float* n2   = n1 + BB * HH * SS;

    float* ctx   = (float*)d_out;
    float* probs = ctx + CTX_ELEMS;

    proj_kernel<<<dim3(32, 24), 256, 0, stream>>>(hs, Wq, bq, Wk1, bk1, Wk2, bk2,
                                                  Wv, bv, q_ws, k1T, k2T, v_ws);
    norms_kernel<<<dim3(SS / 256, BB * HH), 256, 0, stream>>>(k1T, k2T, n1, n2);
    attn_fused<<<dim3(BB * HH * (SS / RQ)), 256, 0, stream>>>(q_ws, k1T, k2T,
                                                              n1, n2, mask, pi,
                                                              v_ws, probs, ctx);
}